// Round 2
// baseline (2635.309 us; speedup 1.0000x reference)
//
#include <hip/hip_runtime.h>

#define TAU 0.25f
#define OMT 0.75f

typedef __attribute__((ext_vector_type(8))) short  bfrag8;   // 8 bf16 = 4 VGPRs (MFMA A/B operand)
typedef __attribute__((ext_vector_type(4))) float  f4acc;    // MFMA C/D
typedef __attribute__((ext_vector_type(4))) float  fvec4;
typedef __attribute__((ext_vector_type(2))) unsigned uvec2;
typedef __attribute__((ext_vector_type(4))) unsigned uvec4;

// d_ws layout (bytes)
#define WS_PACKH 0u         // 32 hps n-tiles * 8 ksteps * 1024B   = 262144
#define WS_PACKS 262144u    // 32 s  n-tiles * 36 ksteps * 1024B   = 1179648
#define WS_PACKC 1441792u   // 8 css n-tiles * 16 ksteps * 1024B   = 131072
#define WS_BIAS  1572864u   // 1152 fp32 (TAU-prescaled), acts-col order

__device__ __forceinline__ unsigned short f2bf(float f) {
    unsigned u = __builtin_bit_cast(unsigned, f);
    u = (u + 0x7FFFu + ((u >> 16) & 1u)) >> 16;   // RNE
    return (unsigned short)u;
}

// ---------------------------------------------------------------------------
// Prep: pack all weights (bf16) into exact MFMA B-fragment stream order so the
// main kernel's B loads are perfectly coalesced 1KB global_load_dwordx4 bursts.
// B-frag layout for mfma_f32_16x16x32_bf16: lane holds B[k=(lane>>4)*8+j][n=lane&15].
// acts-K space: [0,512)=a_hps, [512,1024)=a_s, [1024,1152)=a_css.
// ---------------------------------------------------------------------------
__global__ void hs04_prep(const float* __restrict__ wph, const float* __restrict__ whs,
                          const float* __restrict__ wss, const float* __restrict__ wsc,
                          const float* __restrict__ wcs, const float* __restrict__ bh,
                          const float* __restrict__ bs,  const float* __restrict__ bc,
                          unsigned char* __restrict__ ws)
{
    int gid = blockIdx.x * 256 + threadIdx.x;
    if (gid < 98304) {                       // 1536 frags * 64 lanes
        int lane = gid & 63, frag = gid >> 6;
        int cls, nt, ks; size_t off;
        if (frag < 256)       { cls = 0; nt = frag >> 3;       ks = frag & 7;
                                off = WS_PACKH + (size_t)nt*8192  + (size_t)ks*1024; }
        else if (frag < 1408) { int f = frag - 256;  cls = 1; nt = f / 36; ks = f - nt*36;
                                off = WS_PACKS + (size_t)nt*36864 + (size_t)ks*1024; }
        else                  { int f = frag - 1408; cls = 2; nt = f >> 4; ks = f & 15;
                                off = WS_PACKC + (size_t)nt*16384 + (size_t)ks*1024; }
        int q = lane >> 4, rr = lane & 15;
        unsigned short v[8];
        #pragma unroll
        for (int j = 0; j < 8; ++j) {
            int k = ks*32 + q*8 + j;
            int n = nt*16 + rr;
            float wv;
            if (cls == 0)      wv = wph[k*512 + n];                       // x -> hps
            else if (cls == 1) wv = (k < 512)  ? whs[k*512 + n]
                               : (k < 1024) ? wss[(k-512)*512 + n]
                                            : wcs[(k-1024)*512 + n];      // acts -> s
            else               wv = wsc[k*128 + n];                       // a_s -> css (k local 0..511)
            v[j] = f2bf(wv);
        }
        uvec4 pk = { (unsigned)v[0] | ((unsigned)v[1] << 16),
                     (unsigned)v[2] | ((unsigned)v[3] << 16),
                     (unsigned)v[4] | ((unsigned)v[5] << 16),
                     (unsigned)v[6] | ((unsigned)v[7] << 16) };
        *(uvec4*)(ws + off + (size_t)lane*16) = pk;
    } else if (gid < 98304 + 1152) {
        int col = gid - 98304;
        float b = (col < 512) ? bh[col] : (col < 1024 ? bs[col-512] : bc[col-1024]);
        ((float*)(ws + WS_BIAS))[col] = TAU * b;
    }
}

// ---------------------------------------------------------------------------
// Main: 256 persistent blocks * 64 batch rows. Integrator state (64x1152 fp32)
// lives in MFMA accumulators for all 20 timesteps. Activations (TAU*sigmoid,
// bf16) live in LDS (XOR-swizzled 16B chunks -> 2-way-max bank aliasing).
// Wave w owns all 64 rows x 144 cols: n-tiles {hps w*64+j*16}x4, {s w*64+j*16}x4,
// {css w*16}x1 -> exactly 98304 K-MACs/col-slice per wave (balanced).
// ---------------------------------------------------------------------------
__global__ __launch_bounds__(512, 2) void hs04_main(const float* __restrict__ x_all,
                                                    const unsigned char* __restrict__ ws,
                                                    float* __restrict__ out)
{
    extern __shared__ char smem[];
    char* const acts = smem;              // 64 rows x 1152 bf16, row stride 2304B, swizzled
    char* const xbuf = smem + 147456;     // 2 x (16 rows x 256 bf16 = 8192B), swizzled

    const int tid  = threadIdx.x;
    const int lane = tid & 63;
    const int w    = tid >> 6;
    const int q    = lane >> 4;
    const int r    = lane & 15;
    const int b0   = blockIdx.x << 6;

    // init acts = bf16(TAU*0.5) everywhere (value-uniform -> swizzle irrelevant)
    {
        unsigned hv = f2bf(0.125f);
        unsigned u  = hv | (hv << 16);
        uvec4 fill = {u, u, u, u};
        uvec4* p = (uvec4*)acts;
        for (int i = tid; i < 9216; i += 512) p[i] = fill;
    }

    int colbase[9];
    #pragma unroll
    for (int j = 0; j < 4; ++j) { colbase[j] = w*64 + j*16; colbase[4+j] = 512 + w*64 + j*16; }
    colbase[8] = 1024 + w*16;

    float tb[9];
    {
        const float* bias = (const float*)(ws + WS_BIAS);
        #pragma unroll
        for (int j = 0; j < 9; ++j) tb[j] = bias[colbase[j] + r];
    }

    f4acc acc[9][4];                      // [ntile][mtile]; acc == integrator value `in`
    #pragma unroll
    for (int j = 0; j < 9; ++j)
        #pragma unroll
        for (int m = 0; m < 4; ++m) acc[j][m] = {0.f, 0.f, 0.f, 0.f};

    const bfrag8* bH[4]; const bfrag8* bS[4]; const bfrag8* bC;
    #pragma unroll
    for (int j = 0; j < 4; ++j) {
        bH[j] = (const bfrag8*)(ws + WS_PACKH + (size_t)(w*4+j)*8192)  + lane;
        bS[j] = (const bfrag8*)(ws + WS_PACKS + (size_t)(w*4+j)*36864) + lane;
    }
    bC = (const bfrag8*)(ws + WS_PACKC + (size_t)w*16384) + lane;

    __syncthreads();

    for (int t = 0; t < 20; ++t) {
        // ---- phase 0: leak + bias (acts are TAU-prescaled, so MFMA adds TAU*G)
        #pragma unroll
        for (int j = 0; j < 9; ++j) {
            float tbj = tb[j];
            #pragma unroll
            for (int m = 0; m < 4; ++m) {
                f4acc a = acc[j][m];
                a.x = OMT*a.x + tbj; a.y = OMT*a.y + tbj;
                a.z = OMT*a.z + tbj; a.w = OMT*a.w + tbj;
                acc[j][m] = a;
            }
        }

        // ---- phase 1: hps GEMM, x staged 16 rows at a time (double buffered)
        // x tile = 16 rows x 256 fp32 = 1024 float4; 64 float4 per row ->
        // row = f4i>>6, c4 = f4i&63, k0 = c4*4, chunk = c4>>1 (16B = 8 bf16),
        // intra-chunk byte off = (c4&1)*8, phys = chunk ^ row (XOR swizzle).
        const float* xt = x_all + ((size_t)t*16384 + (size_t)b0) * 256;
        auto stageX = [&](int mt, char* dst) {
            const fvec4* src = (const fvec4*)xt + (size_t)mt*1024;
            #pragma unroll
            for (int i = 0; i < 2; ++i) {
                int f4i = tid + i*512;            // 1024 float4 = 16 rows x 256 fp32
                fvec4 v = src[f4i];
                int row = f4i >> 6;
                int c4  = f4i & 63;
                unsigned lo = (unsigned)f2bf(TAU*v.x) | ((unsigned)f2bf(TAU*v.y) << 16);
                unsigned hi = (unsigned)f2bf(TAU*v.z) | ((unsigned)f2bf(TAU*v.w) << 16);
                int phys = (c4 >> 1) ^ row;
                uvec2 d = {lo, hi};
                *(uvec2*)(dst + row*512 + phys*16 + ((c4 & 1) << 3)) = d;
            }
        };
        stageX(0, xbuf);
        __syncthreads();
        #pragma unroll
        for (int mt = 0; mt < 4; ++mt) {
            if (mt < 3) stageX(mt+1, xbuf + ((mt+1)&1)*8192);
            const char* xb = xbuf + (mt&1)*8192;
            #pragma unroll 2
            for (int ks = 0; ks < 8; ++ks) {
                bfrag8 af = *(const bfrag8*)(xb + r*512 + ((((ks<<2)+q) ^ r) << 4));
                #pragma unroll
                for (int j = 0; j < 4; ++j) {
                    bfrag8 bf = bH[j][ks*64];
                    acc[j][mt] = __builtin_amdgcn_mfma_f32_16x16x32_bf16(af, bf, acc[j][mt], 0, 0, 0);
                }
            }
            __syncthreads();
        }

        // ---- phase 2: s + css GEMM over acts (K = 36 ksteps of 32; css uses k 512..1023)
        #pragma unroll 2
        for (int ks = 0; ks < 36; ++ks) {
            bfrag8 a[4];
            #pragma unroll
            for (int m = 0; m < 4; ++m)
                a[m] = *(const bfrag8*)(acts + (m*16 + r)*2304 + ((((ks<<2)+q) ^ r) << 4));
            #pragma unroll
            for (int j = 0; j < 4; ++j) {
                bfrag8 bf = bS[j][ks*64];
                #pragma unroll
                for (int m = 0; m < 4; ++m)
                    acc[4+j][m] = __builtin_amdgcn_mfma_f32_16x16x32_bf16(a[m], bf, acc[4+j][m], 0, 0, 0);
            }
            if (ks >= 16 && ks < 32) {
                bfrag8 bf = bC[(ks-16)*64];
                #pragma unroll
                for (int m = 0; m < 4; ++m)
                    acc[8][m] = __builtin_amdgcn_mfma_f32_16x16x32_bf16(a[m], bf, acc[8][m], 0, 0, 0);
            }
        }

        // ---- phase 3: sigmoid -> new acts (bf16, TAU-prescaled) + output ticks
        __syncthreads();    // all reads of old acts complete
        {
            const bool emit = (t >= 16);
            #pragma unroll
            for (int j = 0; j < 9; ++j) {
                int col   = colbase[j] + r;       // C/D layout: col = lane&15
                int chunk = col >> 3;
                int coff  = (col & 7) << 1;
                #pragma unroll
                for (int m = 0; m < 4; ++m) {
                    f4acc v = acc[j][m];
                    #pragma unroll
                    for (int e = 0; e < 4; ++e) {
                        int rl  = q*4 + e;        // C/D layout: row = quad*4 + reg
                        int row = m*16 + rl;
                        float in = (e==0)?v.x:(e==1)?v.y:(e==2)?v.z:v.w;
                        float a  = 1.0f / (1.0f + __expf(-in));
                        *(unsigned short*)(acts + row*2304 + ((chunk ^ rl) << 4) + coff) = f2bf(TAU * a);
                        if (emit && j >= 4 && j < 8) {
                            float* op = out + (((size_t)(t-16)*16384 + (size_t)(b0 + row)) * 512);
                            op[col - 512] = a;
                        }
                    }
                }
            }
        }
        __syncthreads();    // new acts visible before next timestep
    }
}

extern "C" void kernel_launch(void* const* d_in, const int* in_sizes, int n_in,
                              void* d_out, int out_size, void* d_ws, size_t ws_size,
                              hipStream_t stream) {
    const float* x   = (const float*)d_in[0];
    const float* wph = (const float*)d_in[1];
    const float* whs = (const float*)d_in[2];
    const float* wss = (const float*)d_in[3];
    const float* wsc = (const float*)d_in[4];
    const float* wcs = (const float*)d_in[5];
    const float* bh  = (const float*)d_in[6];
    const float* bs  = (const float*)d_in[7];
    const float* bc  = (const float*)d_in[8];
    unsigned char* ws = (unsigned char*)d_ws;
    float* outp = (float*)d_out;

    hipFuncSetAttribute((const void*)hs04_main,
                        hipFuncAttributeMaxDynamicSharedMemorySize, 163840);

    hipLaunchKernelGGL(hs04_prep, dim3(389), dim3(256), 0, stream,
                       wph, whs, wss, wsc, wcs, bh, bs, bc, ws);
    hipLaunchKernelGGL(hs04_main, dim3(256), dim3(512), 163840, stream,
                       x, ws, outp);
}